// Round 17
// baseline (150.960 us; speedup 1.0000x reference)
//
#include <hip/hip_runtime.h>

// LocalSelfAttention2d, R17 = R16 two-kernel split with K2 staging FIXED
// (R16 read 16B-strided chunks with an 8B type and wrote LDS rows 0..127 ->
//  OOB -> NaN; now 2048 x 16B bf16x8 chunks, pos in [0,64)).
//  K1 (lsa_qkattn): staging + QKV + attention. ONE barrier. o -> ws bf16.
//  K2 (lsa_out): per-window out-proj GEMM + crop + float4 y stores.
// B=4, CIN=HC=256, heads=8, dh=32, P=8, img 128x128, pad 4/4, 17x17 win.

typedef __attribute__((ext_vector_type(8))) short bf16x8;
typedef __attribute__((ext_vector_type(4))) float f32x4;

#define NWROW 17
#define NWIN  289
#define ATT_SCALE 0.17677669529663687f  // 1/sqrt(32)

// K1 LDS geometry (ushort units)
#define XS_STRIDE 264                    // 528B rows (16B aligned)
#define XS_SIZE   (64 * XS_STRIDE)       // 16896 ush
#define WPRIV     2560                   // per-wave private scratch
#define LDS_USH   (XS_SIZE + 8 * WPRIV)  // 74752 B -> 2 blocks/CU

__device__ __forceinline__ ushort f2bf(float f) {
    unsigned u = __float_as_uint(f);
    u += 0x7FFFu + ((u >> 16) & 1u);   // RNE
    return (ushort)(u >> 16);
}
__device__ __forceinline__ unsigned pack2(float a, float b) {
    return (unsigned)f2bf(a) | ((unsigned)f2bf(b) << 16);
}
__device__ __forceinline__ int xcd_swz(int orig) {
    // bijective XCD chunk swizzle (nwg=1156: q=144, r=4)
    int xcd = orig & 7, idx = orig >> 3;
    return (xcd < 4 ? xcd * 145 : 580 + (xcd - 4) * 144) + idx;
}

__global__ void lsa_wconv(const float* __restrict__ wqkv,
                          const float* __restrict__ wout,
                          ushort* __restrict__ dst)
{
    int n = blockIdx.x * 256 + threadIdx.x;   // 1024 x 256 = 262144
    float v = (n < 196608) ? wqkv[n] : wout[n - 196608];
    dst[n] = f2bf(v);
}

__global__ __launch_bounds__(512, 4)
void lsa_qkattn(const float* __restrict__ x,
                const float* __restrict__ bqkv,
                const float* __restrict__ posb,
                const ushort* __restrict__ wqkvb,
                ushort* __restrict__ ows)
{
    __shared__ __align__(16) ushort sm[LDS_USH];

    const int t    = threadIdx.x;
    const int wv   = t >> 6;        // wave = head
    const int lane = t & 63;
    const int g    = lane >> 4;
    const int c    = lane & 15;
    const int head = wv;

    const int bid = xcd_swz(blockIdx.x);
    const int b   = bid / NWIN;
    const int win = bid - b * NWIN;
    const int wi  = win / NWROW;
    const int wj  = win - wi * NWROW;
    const int hbase = wi * 8 - 4;
    const int wbase = wj * 8 - 4;

    // ---------------- phase 0: stage x tile (bf16 [pos][ch]) ----------------
    #pragma unroll
    for (int i = 0; i < 8; ++i) {
        int id = (i << 9) + t;
        int ch = id >> 4;
        int qd = id & 15;
        int h  = hbase + (qd >> 1);
        int w0 = wbase + (qd & 1) * 4;
        f32x4 v = (f32x4){0.f, 0.f, 0.f, 0.f};
        if ((unsigned)h < 128u && (unsigned)w0 < 125u)
            v = *(const f32x4*)&x[(((size_t)b * 256 + ch) * 128 + h) * 128 + w0];
        ushort bs[4] = {f2bf(v[0]), f2bf(v[1]), f2bf(v[2]), f2bf(v[3])};
        #pragma unroll
        for (int e = 0; e < 4; ++e) {
            int ee = (e + qd) & 3;
            sm[(qd * 4 + ee) * XS_STRIDE + ch] = bs[ee];
        }
    }
    __syncthreads();   // B0 — the ONLY barrier; waves independent after this

    ushort* priv = &sm[XS_SIZE + wv * WPRIV];

    // ---------------- pass A: q,k projection ----------------
    f32x4 acc[4][4];
    #pragma unroll
    for (int i = 0; i < 4; ++i)
        #pragma unroll
        for (int j = 0; j < 4; ++j)
            acc[i][j] = (f32x4){0.f, 0.f, 0.f, 0.f};

    const ushort* wr[4];
    #pragma unroll
    for (int j = 0; j < 4; ++j) {
        int m0 = (j >> 1) * 256 + head * 32 + (j & 1) * 16;
        wr[j] = wqkvb + (size_t)(m0 + c) * 256;
    }

    #pragma unroll
    for (int ks = 0; ks < 8; ++ks) {
        bf16x8 bfr[4];
        #pragma unroll
        for (int pt = 0; pt < 4; ++pt)
            bfr[pt] = *(const bf16x8*)&sm[(pt * 16 + c) * XS_STRIDE + ks * 32 + 8 * g];
        #pragma unroll
        for (int j = 0; j < 4; ++j) {
            bf16x8 afr = *(const bf16x8*)(wr[j] + ks * 32 + 8 * g);
            #pragma unroll
            for (int pt = 0; pt < 4; ++pt)
                acc[j][pt] = __builtin_amdgcn_mfma_f32_16x16x32_bf16(afr, bfr[pt], acc[j][pt], 0, 0, 0);
        }
    }

    // q epilogue -> Qt[pos][32d] stride 40
    #pragma unroll
    for (int mt = 0; mt < 2; ++mt) {
        f32x4 bq = *(const f32x4*)&bqkv[head * 32 + mt * 16 + 4 * g];
        #pragma unroll
        for (int pt = 0; pt < 4; ++pt) {
            const int pos = pt * 16 + c;
            const float* pb = posb + (size_t)(head * 32 + mt * 16 + 4 * g) * 64 + pos;
            float v0 = (acc[mt][pt][0] + bq[0] + pb[0])   * ATT_SCALE;
            float v1 = (acc[mt][pt][1] + bq[1] + pb[64])  * ATT_SCALE;
            float v2 = (acc[mt][pt][2] + bq[2] + pb[128]) * ATT_SCALE;
            float v3 = (acc[mt][pt][3] + bq[3] + pb[192]) * ATT_SCALE;
            *(unsigned*)&priv[pos * 40 + mt * 16 + 4 * g]     = pack2(v0, v1);
            *(unsigned*)&priv[pos * 40 + mt * 16 + 4 * g + 2] = pack2(v2, v3);
        }
    }
    bf16x8 qf[4];
    #pragma unroll
    for (int qt = 0; qt < 4; ++qt)
        qf[qt] = *(const bf16x8*)&priv[(qt * 16 + c) * 40 + 8 * g];

    // k epilogue -> Kt (same slots)
    #pragma unroll
    for (int mt = 0; mt < 2; ++mt) {
        f32x4 bk = *(const f32x4*)&bqkv[256 + head * 32 + mt * 16 + 4 * g];
        #pragma unroll
        for (int pt = 0; pt < 4; ++pt) {
            const int pos = pt * 16 + c;
            *(unsigned*)&priv[pos * 40 + mt * 16 + 4 * g]     = pack2(acc[mt + 2][pt][0] + bk[0], acc[mt + 2][pt][1] + bk[1]);
            *(unsigned*)&priv[pos * 40 + mt * 16 + 4 * g + 2] = pack2(acc[mt + 2][pt][2] + bk[2], acc[mt + 2][pt][3] + bk[3]);
        }
    }
    bf16x8 kf[4];
    #pragma unroll
    for (int kt = 0; kt < 4; ++kt)
        kf[kt] = *(const bf16x8*)&priv[(kt * 16 + c) * 40 + 8 * g];

    // ---------------- pass B: v projection ----------------
    f32x4 av[2][4];
    #pragma unroll
    for (int i = 0; i < 2; ++i)
        #pragma unroll
        for (int j = 0; j < 4; ++j)
            av[i][j] = (f32x4){0.f, 0.f, 0.f, 0.f};
    const ushort* wv0 = wqkvb + (size_t)(512 + head * 32 + c) * 256;
    const ushort* wv1 = wqkvb + (size_t)(512 + head * 32 + 16 + c) * 256;

    #pragma unroll
    for (int ks = 0; ks < 8; ++ks) {
        bf16x8 bfr[4];
        #pragma unroll
        for (int pt = 0; pt < 4; ++pt)
            bfr[pt] = *(const bf16x8*)&sm[(pt * 16 + c) * XS_STRIDE + ks * 32 + 8 * g];
        bf16x8 a0 = *(const bf16x8*)(wv0 + ks * 32 + 8 * g);
        bf16x8 a1 = *(const bf16x8*)(wv1 + ks * 32 + 8 * g);
        #pragma unroll
        for (int pt = 0; pt < 4; ++pt) {
            av[0][pt] = __builtin_amdgcn_mfma_f32_16x16x32_bf16(a0, bfr[pt], av[0][pt], 0, 0, 0);
            av[1][pt] = __builtin_amdgcn_mfma_f32_16x16x32_bf16(a1, bfr[pt], av[1][pt], 0, 0, 0);
        }
    }

    // v epilogue -> VT[32 d][64 pos] stride 72 (overwrites Qt/Kt; qf/kf in regs)
    #pragma unroll
    for (int mt = 0; mt < 2; ++mt) {
        f32x4 bv = *(const f32x4*)&bqkv[512 + head * 32 + mt * 16 + 4 * g];
        #pragma unroll
        for (int pt = 0; pt < 4; ++pt) {
            #pragma unroll
            for (int r = 0; r < 4; ++r)
                priv[(mt * 16 + 4 * g + r) * 72 + pt * 16 + c] = f2bf(av[mt][pt][r] + bv[r]);
        }
    }

    // ---------------- attention (wave-private) ----------------
    f32x4 s[4][4];
    #pragma unroll
    for (int kt = 0; kt < 4; ++kt)
        #pragma unroll
        for (int qt = 0; qt < 4; ++qt)
            s[kt][qt] = __builtin_amdgcn_mfma_f32_16x16x32_bf16(kf[kt], qf[qt],
                                                                (f32x4){0.f,0.f,0.f,0.f}, 0, 0, 0);

    float rinv[4];
    #pragma unroll
    for (int qt = 0; qt < 4; ++qt) {
        float mx = s[0][qt][0];
        #pragma unroll
        for (int kt = 0; kt < 4; ++kt)
            #pragma unroll
            for (int r = 0; r < 4; ++r)
                mx = fmaxf(mx, s[kt][qt][r]);
        mx = fmaxf(mx, __shfl_xor(mx, 16));
        mx = fmaxf(mx, __shfl_xor(mx, 32));
        float sum = 0.f;
        #pragma unroll
        for (int kt = 0; kt < 4; ++kt)
            #pragma unroll
            for (int r = 0; r < 4; ++r) {
                s[kt][qt][r] = __expf(s[kt][qt][r] - mx);
                sum += s[kt][qt][r];
            }
        sum += __shfl_xor(sum, 16);
        sum += __shfl_xor(sum, 32);
        rinv[qt] = 1.0f / sum;
    }

    bf16x8 vf[2][2];
    #pragma unroll
    for (int dt = 0; dt < 2; ++dt)
        #pragma unroll
        for (int k2 = 0; k2 < 2; ++k2)
            vf[dt][k2] = *(const bf16x8*)&priv[(dt * 16 + c) * 72 + k2 * 32 + 8 * g];

    f32x4 o[2][4];
    #pragma unroll
    for (int dt = 0; dt < 2; ++dt)
        #pragma unroll
        for (int qt = 0; qt < 4; ++qt)
            o[dt][qt] = (f32x4){0.f,0.f,0.f,0.f};

    #pragma unroll
    for (int k2 = 0; k2 < 2; ++k2) {
        #pragma unroll
        for (int qt = 0; qt < 4; ++qt)
            #pragma unroll
            for (int kl = 0; kl < 2; ++kl) {
                const int kt = k2 * 2 + kl;
                *(unsigned*)&priv[(qt * 16 + c) * 40 + kl * 16 + 4 * g]     = pack2(s[kt][qt][0], s[kt][qt][1]);
                *(unsigned*)&priv[(qt * 16 + c) * 40 + kl * 16 + 4 * g + 2] = pack2(s[kt][qt][2], s[kt][qt][3]);
            }
        #pragma unroll
        for (int qt = 0; qt < 4; ++qt) {
            bf16x8 pf = *(const bf16x8*)&priv[(qt * 16 + c) * 40 + 8 * g];
            #pragma unroll
            for (int dt = 0; dt < 2; ++dt)
                o[dt][qt] = __builtin_amdgcn_mfma_f32_16x16x32_bf16(vf[dt][k2], pf, o[dt][qt], 0, 0, 0);
        }
    }

    // o -> global ws [b][win][pos][ch] bf16 (no barrier; wave retires)
    ushort* ow = ows + (size_t)(b * NWIN + win) * 16384;
    #pragma unroll
    for (int dt = 0; dt < 2; ++dt)
        #pragma unroll
        for (int qt = 0; qt < 4; ++qt) {
            const int pos = qt * 16 + c;
            const int ch0 = head * 32 + dt * 16 + 4 * g;
            float rv = rinv[qt];
            *(uint2*)&ow[pos * 256 + ch0] =
                make_uint2(pack2(o[dt][qt][0]*rv, o[dt][qt][1]*rv),
                           pack2(o[dt][qt][2]*rv, o[dt][qt][3]*rv));
        }
}

__global__ __launch_bounds__(256, 4)
void lsa_out(const ushort* __restrict__ ows,
             const ushort* __restrict__ woutb,
             const float* __restrict__ bout,
             float* __restrict__ y)
{
    __shared__ __align__(16) ushort os[64 * XS_STRIDE];  // 33792 B -> 4 blocks/CU

    const int t    = threadIdx.x;
    const int wv   = t >> 6;        // 0..3, owns 64 out-channels
    const int lane = t & 63;
    const int g    = lane >> 4;
    const int c    = lane & 15;

    const int bid = xcd_swz(blockIdx.x);
    const int b   = bid / NWIN;
    const int win = bid - b * NWIN;
    const int wi  = win / NWROW;
    const int wj  = win - wi * NWROW;
    const int wbase = wj * 8 - 4;

    // stage o tile: 2048 x 16B coalesced chunks (FIXED: pos in [0,64))
    const ushort* src = ows + (size_t)(b * NWIN + win) * 16384;
    #pragma unroll
    for (int j = 0; j < 8; ++j) {
        int chunk = j * 256 + t;          // 0..2047
        int pos = chunk >> 5;             // 0..63
        int ch0 = (chunk & 31) * 8;       // 0..248
        *(bf16x8*)&os[pos * XS_STRIDE + ch0] = *(const bf16x8*)&src[chunk * 8];
    }
    __syncthreads();   // B0

    // out-proj: wave owns co = wv*64 .. +63 (4 m-tiles), K=256
    f32x4 ya[4][4];
    #pragma unroll
    for (int i = 0; i < 4; ++i)
        #pragma unroll
        for (int j = 0; j < 4; ++j)
            ya[i][j] = (f32x4){0.f,0.f,0.f,0.f};

    const ushort* wo[4];
    #pragma unroll
    for (int mt = 0; mt < 4; ++mt)
        wo[mt] = woutb + (size_t)(wv * 64 + mt * 16 + c) * 256;

    #pragma unroll
    for (int ks = 0; ks < 8; ++ks) {
        bf16x8 ofr[4];
        #pragma unroll
        for (int pt = 0; pt < 4; ++pt)
            ofr[pt] = *(const bf16x8*)&os[(pt * 16 + c) * XS_STRIDE + ks * 32 + 8 * g];
        #pragma unroll
        for (int mt = 0; mt < 4; ++mt) {
            bf16x8 afr = *(const bf16x8*)(wo[mt] + ks * 32 + 8 * g);
            #pragma unroll
            for (int pt = 0; pt < 4; ++pt)
                ya[mt][pt] = __builtin_amdgcn_mfma_f32_16x16x32_bf16(afr, ofr[pt], ya[mt][pt], 0, 0, 0);
        }
    }
    __syncthreads();   // B1: os reads done; ys overlays

    // epilogue: per-wave transpose -> float4 y stores with crop
    float* ysp = (float*)&os[wv * 2112];   // 16 rows x 66 f32 = 4224 B per wave
    #pragma unroll
    for (int mt = 0; mt < 4; ++mt) {
        f32x4 bo = *(const f32x4*)&bout[wv * 64 + mt * 16 + 4 * g];
        #pragma unroll
        for (int pt = 0; pt < 4; ++pt) {
            const int pos = pt * 16 + c;
            #pragma unroll
            for (int r = 0; r < 4; ++r)
                ysp[(4 * g + r) * 66 + pos] = ya[mt][pt][r] + bo[r];
        }
        #pragma unroll
        for (int k = 0; k < 2; ++k) {
            const int cl = k * 8 + (lane >> 3);
            const int hh = lane & 7;
            float2 p0 = *(float2*)&ysp[cl * 66 + hh * 8];
            float2 p1 = *(float2*)&ysp[cl * 66 + hh * 8 + 2];
            float2 p2 = *(float2*)&ysp[cl * 66 + hh * 8 + 4];
            float2 p3 = *(float2*)&ysp[cl * 66 + hh * 8 + 6];
            const int co  = wv * 64 + mt * 16 + cl;
            const int him = wi * 8 + hh - 4;
            if ((unsigned)him < 128u) {
                float* yrow = y + (((size_t)b * 256 + co) * 128 + him) * 128;
                if (wj > 0)  { f32x4 v0 = {p0.x, p0.y, p1.x, p1.y}; *(f32x4*)&yrow[wbase]     = v0; }
                if (wj < 16) { f32x4 v1 = {p2.x, p2.y, p3.x, p3.y}; *(f32x4*)&yrow[wbase + 4] = v1; }
            }
        }
        // rows are wave-private and re-written next mt; in-order DS pipe orders RAW
    }
}

extern "C" void kernel_launch(void* const* d_in, const int* in_sizes, int n_in,
                              void* d_out, int out_size, void* d_ws, size_t ws_size,
                              hipStream_t stream)
{
    const float* x    = (const float*)d_in[0];
    const float* wqkv = (const float*)d_in[1];
    const float* bqkv = (const float*)d_in[2];
    const float* posb = (const float*)d_in[3];
    const float* wout = (const float*)d_in[4];
    const float* bout = (const float*)d_in[5];
    float* y = (float*)d_out;

    ushort* wqkvb = (ushort*)d_ws;            // 196608 bf16
    ushort* woutb = wqkvb + 196608;           // 65536 bf16
    ushort* ows   = wqkvb + 262144;           // 4*289*16384 bf16 = 37.9 MB

    lsa_wconv<<<dim3(1024), dim3(256), 0, stream>>>(wqkv, wout, wqkvb);
    lsa_qkattn<<<dim3(4 * NWIN), dim3(512), 0, stream>>>(x, bqkv, posb, wqkvb, ows);
    lsa_out<<<dim3(4 * NWIN), dim3(256), 0, stream>>>(ows, woutb, bout, y);
}

// Round 18
// 125.851 us; speedup vs baseline: 1.1995x; 1.1995x over previous
//
#include <hip/hip_runtime.h>

// LocalSelfAttention2d fused MFMA — FINAL (R18 = R13, the session's best: 125.9us).
// B=4, CIN=HC=256, heads=8, dh=32, P=8, img 128x128, pad 4/4, 17x17 windows.
//
// Structure: block = (b,window), 512 thr, wave = head, 3 barriers total.
// Per-wave private 2560-ush LDS slice reused in sequential generations
// (same-wave RAW via in-order DS pipe): Qt[64x32 s40] -> qf -> Kt -> kf ->
// VT[32x64 s72] -> vf -> P0/P1[64x32 s40] -> pf. o overlays xs after B1;
// out-proj accumulates in regs; y-transpose via the wave's private slice
// (no barrier needed after out-proj).
//
// Session ledger (counter-verified): barrier cuts 13->4->3 were the only wins;
// 32x32 MFMA, conflict swizzles, prefetch, setprio, uint2, bpermute-redist,
// and a 2-kernel split all regressed (spills at the 128-unified-reg cap, or
// scheduler perturbation, or lost fused overlap). Latency-bound plateau:
// MFMA 12% / VALU 19% / HBM 11% busy.

typedef __attribute__((ext_vector_type(8))) short bf16x8;
typedef __attribute__((ext_vector_type(4))) float f32x4;

#define NWROW 17
#define NWIN  289
#define ATT_SCALE 0.17677669529663687f  // 1/sqrt(32)

// LDS geometry (ushort units)
#define XS_STRIDE 264                    // 528B rows (16B aligned)
#define XS_SIZE   (64 * XS_STRIDE)       // 16896 ush = 33792 B (os overlays this)
#define WPRIV     2560                   // per-wave private scratch (5120 B)
#define LDS_USH   (XS_SIZE + 8 * WPRIV)  // 37376 ush = 74752 B -> 2 blocks/CU

__device__ __forceinline__ ushort f2bf(float f) {
    unsigned u = __float_as_uint(f);
    u += 0x7FFFu + ((u >> 16) & 1u);   // RNE
    return (ushort)(u >> 16);
}
__device__ __forceinline__ unsigned pack2(float a, float b) {
    return (unsigned)f2bf(a) | ((unsigned)f2bf(b) << 16);
}

__global__ void lsa_wconv(const float* __restrict__ wqkv,
                          const float* __restrict__ wout,
                          ushort* __restrict__ dst)
{
    int n = blockIdx.x * 256 + threadIdx.x;   // 1024 x 256 = 262144
    float v = (n < 196608) ? wqkv[n] : wout[n - 196608];
    dst[n] = f2bf(v);
}

__global__ __launch_bounds__(512, 4)
void lsa_fused(const float* __restrict__ x,
               const float* __restrict__ bqkv,
               const float* __restrict__ posb,
               const float* __restrict__ bout,
               const ushort* __restrict__ wqkvb,
               const ushort* __restrict__ woutb,
               float* __restrict__ y)
{
    __shared__ __align__(16) ushort sm[LDS_USH];

    const int t    = threadIdx.x;
    const int wv   = t >> 6;        // wave = head
    const int lane = t & 63;
    const int g    = lane >> 4;     // 0..3
    const int c    = lane & 15;     // 0..15
    const int head = wv;

    // bijective XCD chunk swizzle (nwg=1156: q=144, r=4)
    const int orig = blockIdx.x;
    const int xcd  = orig & 7;
    const int idx  = orig >> 3;
    const int bid  = (xcd < 4 ? xcd * 145 : 580 + (xcd - 4) * 144) + idx;

    const int b   = bid / NWIN;
    const int win = bid - b * NWIN;
    const int wi  = win / NWROW;
    const int wj  = win - wi * NWROW;
    const int hbase = wi * 8 - 4;
    const int wbase = wj * 8 - 4;

    // ---------------- phase 0: stage x tile (bf16 [pos][ch]) ----------------
    #pragma unroll
    for (int i = 0; i < 8; ++i) {
        int id = (i << 9) + t;
        int ch = id >> 4;
        int qd = id & 15;           // hh = qd>>1, wquad = qd&1
        int h  = hbase + (qd >> 1);
        int w0 = wbase + (qd & 1) * 4;
        f32x4 v = (f32x4){0.f, 0.f, 0.f, 0.f};
        if ((unsigned)h < 128u && (unsigned)w0 < 125u)
            v = *(const f32x4*)&x[(((size_t)b * 256 + ch) * 128 + h) * 128 + w0];
        ushort bs[4] = {f2bf(v[0]), f2bf(v[1]), f2bf(v[2]), f2bf(v[3])};
        #pragma unroll
        for (int e = 0; e < 4; ++e) {
            int ee = (e + qd) & 3;
            sm[(qd * 4 + ee) * XS_STRIDE + ch] = bs[ee];
        }
    }
    __syncthreads();   // B0

    ushort* priv = &sm[XS_SIZE + wv * WPRIV];

    // ---------------- pass A: q,k projection (4 m-tiles x 4 p-tiles) ----------------
    f32x4 acc[4][4];
    #pragma unroll
    for (int i = 0; i < 4; ++i)
        #pragma unroll
        for (int j = 0; j < 4; ++j)
            acc[i][j] = (f32x4){0.f, 0.f, 0.f, 0.f};

    const ushort* wr[4];
    #pragma unroll
    for (int j = 0; j < 4; ++j) {
        int m0 = (j >> 1) * 256 + head * 32 + (j & 1) * 16;   // sect 0=q,1=k
        wr[j] = wqkvb + (size_t)(m0 + c) * 256;
    }

    #pragma unroll
    for (int ks = 0; ks < 8; ++ks) {
        bf16x8 bfr[4];
        #pragma unroll
        for (int pt = 0; pt < 4; ++pt)
            bfr[pt] = *(const bf16x8*)&sm[(pt * 16 + c) * XS_STRIDE + ks * 32 + 8 * g];
        #pragma unroll
        for (int j = 0; j < 4; ++j) {
            bf16x8 afr = *(const bf16x8*)(wr[j] + ks * 32 + 8 * g);
            #pragma unroll
            for (int pt = 0; pt < 4; ++pt)
                acc[j][pt] = __builtin_amdgcn_mfma_f32_16x16x32_bf16(afr, bfr[pt], acc[j][pt], 0, 0, 0);
        }
    }

    // q epilogue -> Qt[pos][32d] stride 40 (injective: row len 32 <= 40)
    #pragma unroll
    for (int mt = 0; mt < 2; ++mt) {
        f32x4 bq = *(const f32x4*)&bqkv[head * 32 + mt * 16 + 4 * g];
        #pragma unroll
        for (int pt = 0; pt < 4; ++pt) {
            const int pos = pt * 16 + c;
            const float* pb = posb + (size_t)(head * 32 + mt * 16 + 4 * g) * 64 + pos;
            float v0 = (acc[mt][pt][0] + bq[0] + pb[0])   * ATT_SCALE;
            float v1 = (acc[mt][pt][1] + bq[1] + pb[64])  * ATT_SCALE;
            float v2 = (acc[mt][pt][2] + bq[2] + pb[128]) * ATT_SCALE;
            float v3 = (acc[mt][pt][3] + bq[3] + pb[192]) * ATT_SCALE;
            *(unsigned*)&priv[pos * 40 + mt * 16 + 4 * g]     = pack2(v0, v1);
            *(unsigned*)&priv[pos * 40 + mt * 16 + 4 * g + 2] = pack2(v2, v3);
        }
    }
    bf16x8 qf[4];
    #pragma unroll
    for (int qt = 0; qt < 4; ++qt)
        qf[qt] = *(const bf16x8*)&priv[(qt * 16 + c) * 40 + 8 * g];

    // k epilogue -> Kt (same slots; same-wave RAW through in-order DS pipe)
    #pragma unroll
    for (int mt = 0; mt < 2; ++mt) {
        f32x4 bk = *(const f32x4*)&bqkv[256 + head * 32 + mt * 16 + 4 * g];
        #pragma unroll
        for (int pt = 0; pt < 4; ++pt) {
            const int pos = pt * 16 + c;
            *(unsigned*)&priv[pos * 40 + mt * 16 + 4 * g]     = pack2(acc[mt + 2][pt][0] + bk[0], acc[mt + 2][pt][1] + bk[1]);
            *(unsigned*)&priv[pos * 40 + mt * 16 + 4 * g + 2] = pack2(acc[mt + 2][pt][2] + bk[2], acc[mt + 2][pt][3] + bk[3]);
        }
    }
    bf16x8 kf[4];
    #pragma unroll
    for (int kt = 0; kt < 4; ++kt)
        kf[kt] = *(const bf16x8*)&priv[(kt * 16 + c) * 40 + 8 * g];

    // ---------------- pass B: v projection (2 m-tiles x 4 p-tiles) ----------------
    f32x4 av[2][4];
    #pragma unroll
    for (int i = 0; i < 2; ++i)
        #pragma unroll
        for (int j = 0; j < 4; ++j)
            av[i][j] = (f32x4){0.f, 0.f, 0.f, 0.f};
    const ushort* wv0 = wqkvb + (size_t)(512 + head * 32 + c) * 256;
    const ushort* wv1 = wqkvb + (size_t)(512 + head * 32 + 16 + c) * 256;

    #pragma unroll
    for (int ks = 0; ks < 8; ++ks) {
        bf16x8 bfr[4];
        #pragma unroll
        for (int pt = 0; pt < 4; ++pt)
            bfr[pt] = *(const bf16x8*)&sm[(pt * 16 + c) * XS_STRIDE + ks * 32 + 8 * g];
        bf16x8 a0 = *(const bf16x8*)(wv0 + ks * 32 + 8 * g);
        bf16x8 a1 = *(const bf16x8*)(wv1 + ks * 32 + 8 * g);
        #pragma unroll
        for (int pt = 0; pt < 4; ++pt) {
            av[0][pt] = __builtin_amdgcn_mfma_f32_16x16x32_bf16(a0, bfr[pt], av[0][pt], 0, 0, 0);
            av[1][pt] = __builtin_amdgcn_mfma_f32_16x16x32_bf16(a1, bfr[pt], av[1][pt], 0, 0, 0);
        }
    }

    // v epilogue -> VT[32 d][64 pos] STRIDE 72 (injective; overwrites Qt/Kt)
    #pragma unroll
    for (int mt = 0; mt < 2; ++mt) {
        f32x4 bv = *(const f32x4*)&bqkv[512 + head * 32 + mt * 16 + 4 * g];
        #pragma unroll
        for (int pt = 0; pt < 4; ++pt) {
            #pragma unroll
            for (int r = 0; r < 4; ++r)
                priv[(mt * 16 + 4 * g + r) * 72 + pt * 16 + c] = f2bf(av[mt][pt][r] + bv[r]);
        }
    }

    // ---------------- attention (fully wave-private, no barriers) ----------------
    f32x4 s[4][4];   // [kt][qt]: D row = key kt*16+4g+r, col = query qt*16+c
    #pragma unroll
    for (int kt = 0; kt < 4; ++kt)
        #pragma unroll
        for (int qt = 0; qt < 4; ++qt)
            s[kt][qt] = __builtin_amdgcn_mfma_f32_16x16x32_bf16(kf[kt], qf[qt],
                                                                (f32x4){0.f,0.f,0.f,0.f}, 0, 0, 0);

    float rinv[4];
    #pragma unroll
    for (int qt = 0; qt < 4; ++qt) {
        float mx = s[0][qt][0];
        #pragma unroll
        for (int kt = 0; kt < 4; ++kt)
            #pragma unroll
            for (int r = 0; r < 4; ++r)
                mx = fmaxf(mx, s[kt][qt][r]);
        mx = fmaxf(mx, __shfl_xor(mx, 16));
        mx = fmaxf(mx, __shfl_xor(mx, 32));
        float sum = 0.f;
        #pragma unroll
        for (int kt = 0; kt < 4; ++kt)
            #pragma unroll
            for (int r = 0; r < 4; ++r) {
                s[kt][qt][r] = __expf(s[kt][qt][r] - mx);
                sum += s[kt][qt][r];
            }
        sum += __shfl_xor(sum, 16);
        sum += __shfl_xor(sum, 32);
        rinv[qt] = 1.0f / sum;
    }

    // vf BEFORE P overwrites VT
    bf16x8 vf[2][2];
    #pragma unroll
    for (int dt = 0; dt < 2; ++dt)
        #pragma unroll
        for (int k2 = 0; k2 < 2; ++k2)
            vf[dt][k2] = *(const bf16x8*)&priv[(dt * 16 + c) * 72 + k2 * 32 + 8 * g];

    // PV in two sequential key-half generations through the same P slots
    f32x4 o[2][4];
    #pragma unroll
    for (int dt = 0; dt < 2; ++dt)
        #pragma unroll
        for (int qt = 0; qt < 4; ++qt)
            o[dt][qt] = (f32x4){0.f,0.f,0.f,0.f};

    #pragma unroll
    for (int k2 = 0; k2 < 2; ++k2) {
        #pragma unroll
        for (int qt = 0; qt < 4; ++qt)
            #pragma unroll
            for (int kl = 0; kl < 2; ++kl) {
                const int kt = k2 * 2 + kl;
                *(unsigned*)&priv[(qt * 16 + c) * 40 + kl * 16 + 4 * g]     = pack2(s[kt][qt][0], s[kt][qt][1]);
                *(unsigned*)&priv[(qt * 16 + c) * 40 + kl * 16 + 4 * g + 2] = pack2(s[kt][qt][2], s[kt][qt][3]);
            }
        #pragma unroll
        for (int qt = 0; qt < 4; ++qt) {
            bf16x8 pf = *(const bf16x8*)&priv[(qt * 16 + c) * 40 + 8 * g];
            #pragma unroll
            for (int dt = 0; dt < 2; ++dt)
                o[dt][qt] = __builtin_amdgcn_mfma_f32_16x16x32_bf16(vf[dt][k2], pf, o[dt][qt], 0, 0, 0);
        }
    }

    __syncthreads();   // B1: every wave done reading xs; o may overlay it

    // o -> os[pos][ch] (xs overlay)
    #pragma unroll
    for (int dt = 0; dt < 2; ++dt)
        #pragma unroll
        for (int qt = 0; qt < 4; ++qt) {
            const int pos = qt * 16 + c;
            const int ch0 = head * 32 + dt * 16 + 4 * g;
            float rv = rinv[qt];
            *(unsigned*)&sm[pos * XS_STRIDE + ch0]     = pack2(o[dt][qt][0]*rv, o[dt][qt][1]*rv);
            *(unsigned*)&sm[pos * XS_STRIDE + ch0 + 2] = pack2(o[dt][qt][2]*rv, o[dt][qt][3]*rv);
        }
    __syncthreads();   // B2: os complete

    // ---------------- out projection: wave owns out-ch wv*32..+31, K=256 ----------------
    f32x4 ya[2][4];
    #pragma unroll
    for (int i = 0; i < 2; ++i)
        #pragma unroll
        for (int j = 0; j < 4; ++j)
            ya[i][j] = (f32x4){0.f,0.f,0.f,0.f};

    const ushort* wo0 = woutb + (size_t)(wv * 32 + c) * 256;
    const ushort* wo1 = woutb + (size_t)(wv * 32 + 16 + c) * 256;

    #pragma unroll
    for (int ks = 0; ks < 8; ++ks) {
        bf16x8 ofr[4];
        #pragma unroll
        for (int pt = 0; pt < 4; ++pt)
            ofr[pt] = *(const bf16x8*)&sm[(pt * 16 + c) * XS_STRIDE + ks * 32 + 8 * g];
        bf16x8 a0 = *(const bf16x8*)(wo0 + ks * 32 + 8 * g);
        bf16x8 a1 = *(const bf16x8*)(wo1 + ks * 32 + 8 * g);
        #pragma unroll
        for (int pt = 0; pt < 4; ++pt) {
            ya[0][pt] = __builtin_amdgcn_mfma_f32_16x16x32_bf16(a0, ofr[pt], ya[0][pt], 0, 0, 0);
            ya[1][pt] = __builtin_amdgcn_mfma_f32_16x16x32_bf16(a1, ofr[pt], ya[1][pt], 0, 0, 0);
        }
    }
    // NO B3: y-transpose scratch is the wave's private slice (priv dead after PV)

    // ---------------- epilogue: per-wave transpose in priv -> float4 y stores ----------------
    float* ysp = (float*)priv;        // [16 rows][66] f32 = 4224B <= 5120B, wave-private
    #pragma unroll
    for (int mt = 0; mt < 2; ++mt) {
        f32x4 bo = *(const f32x4*)&bout[wv * 32 + mt * 16 + 4 * g];
        #pragma unroll
        for (int pt = 0; pt < 4; ++pt) {
            const int pos = pt * 16 + c;
            #pragma unroll
            for (int r = 0; r < 4; ++r)
                ysp[(4 * g + r) * 66 + pos] = ya[mt][pt][r] + bo[r];
        }
        #pragma unroll
        for (int k = 0; k < 2; ++k) {
            const int cl = k * 8 + (lane >> 3);   // 0..15 local out-channel
            const int hh = lane & 7;
            float2 p0 = *(float2*)&ysp[cl * 66 + hh * 8];
            float2 p1 = *(float2*)&ysp[cl * 66 + hh * 8 + 2];
            float2 p2 = *(float2*)&ysp[cl * 66 + hh * 8 + 4];
            float2 p3 = *(float2*)&ysp[cl * 66 + hh * 8 + 6];
            const int co  = wv * 32 + mt * 16 + cl;
            const int him = wi * 8 + hh - 4;
            if ((unsigned)him < 128u) {
                float* yrow = y + (((size_t)b * 256 + co) * 128 + him) * 128;
                if (wj > 0)  { f32x4 v0 = {p0.x, p0.y, p1.x, p1.y}; *(f32x4*)&yrow[wbase]     = v0; }
                if (wj < 16) { f32x4 v1 = {p2.x, p2.y, p3.x, p3.y}; *(f32x4*)&yrow[wbase + 4] = v1; }
            }
        }
    }
}

extern "C" void kernel_launch(void* const* d_in, const int* in_sizes, int n_in,
                              void* d_out, int out_size, void* d_ws, size_t ws_size,
                              hipStream_t stream)
{
    const float* x    = (const float*)d_in[0];
    const float* wqkv = (const float*)d_in[1];
    const float* bqkv = (const float*)d_in[2];
    const float* posb = (const float*)d_in[3];
    const float* wout = (const float*)d_in[4];
    const float* bout = (const float*)d_in[5];
    float* y = (float*)d_out;

    ushort* wqkvb = (ushort*)d_ws;            // 196608 bf16
    ushort* woutb = wqkvb + 196608;           // 65536 bf16

    lsa_wconv<<<dim3(1024), dim3(256), 0, stream>>>(wqkv, wout, wqkvb);
    lsa_fused<<<dim3(4 * NWIN), dim3(512), 0, stream>>>(x, bqkv, posb, bout, wqkvb, woutb, y);
}

// Round 19
// 125.591 us; speedup vs baseline: 1.2020x; 1.0021x over previous
//
#include <hip/hip_runtime.h>

// LocalSelfAttention2d fused MFMA — R19 = R13/R18 anchor + vectorized weight
// preconvert (f32x4/ushort4, 4 elems/thread, 256 blocks vs 1024 scalar).
// lsa_fused byte-identical to the 125.9us anchor.
// B=4, CIN=HC=256, heads=8, dh=32, P=8, img 128x128, pad 4/4, 17x17 windows.
//
// Structure: block = (b,window), 512 thr, wave = head, 3 barriers total.
// Per-wave private 2560-ush LDS slice reused in sequential generations
// (same-wave RAW via in-order DS pipe): Qt[64x32 s40] -> qf -> Kt -> kf ->
// VT[32x64 s72] -> vf -> P0/P1[64x32 s40] -> pf. o overlays xs after B1;
// out-proj accumulates in regs; y-transpose via the wave's private slice.
//
// Session ledger (counter-verified): barrier cuts 13->4->3 were the only wins;
// 32x32 MFMA, conflict swizzles, prefetch, setprio, uint2, bpermute-redist,
// and a 2-kernel split all regressed (spills at the 128-unified-reg cap, or
// scheduler perturbation, or lost fused overlap). Latency-bound plateau:
// MFMA 12% / VALU 19% / HBM 11% busy.

typedef __attribute__((ext_vector_type(8))) short bf16x8;
typedef __attribute__((ext_vector_type(4))) float f32x4;

#define NWROW 17
#define NWIN  289
#define ATT_SCALE 0.17677669529663687f  // 1/sqrt(32)

// LDS geometry (ushort units)
#define XS_STRIDE 264                    // 528B rows (16B aligned)
#define XS_SIZE   (64 * XS_STRIDE)       // 16896 ush = 33792 B (os overlays this)
#define WPRIV     2560                   // per-wave private scratch (5120 B)
#define LDS_USH   (XS_SIZE + 8 * WPRIV)  // 37376 ush = 74752 B -> 2 blocks/CU

__device__ __forceinline__ ushort f2bf(float f) {
    unsigned u = __float_as_uint(f);
    u += 0x7FFFu + ((u >> 16) & 1u);   // RNE
    return (ushort)(u >> 16);
}
__device__ __forceinline__ unsigned pack2(float a, float b) {
    return (unsigned)f2bf(a) | ((unsigned)f2bf(b) << 16);
}

__global__ void lsa_wconv(const float* __restrict__ wqkv,
                          const float* __restrict__ wout,
                          ushort* __restrict__ dst)
{
    // 256 blocks x 256 thr x 4 elems = 262144; 196608 % 4 == 0 (no straddle)
    int n4 = blockIdx.x * 256 + threadIdx.x;   // chunk index, 0..65535
    int n  = n4 * 4;
    f32x4 v = (n < 196608) ? *(const f32x4*)&wqkv[n]
                           : *(const f32x4*)&wout[n - 196608];
    ushort4 o;
    o.x = f2bf(v[0]); o.y = f2bf(v[1]); o.z = f2bf(v[2]); o.w = f2bf(v[3]);
    *(ushort4*)&dst[n] = o;
}

__global__ __launch_bounds__(512, 4)
void lsa_fused(const float* __restrict__ x,
               const float* __restrict__ bqkv,
               const float* __restrict__ posb,
               const float* __restrict__ bout,
               const ushort* __restrict__ wqkvb,
               const ushort* __restrict__ woutb,
               float* __restrict__ y)
{
    __shared__ __align__(16) ushort sm[LDS_USH];

    const int t    = threadIdx.x;
    const int wv   = t >> 6;        // wave = head
    const int lane = t & 63;
    const int g    = lane >> 4;     // 0..3
    const int c    = lane & 15;     // 0..15
    const int head = wv;

    // bijective XCD chunk swizzle (nwg=1156: q=144, r=4)
    const int orig = blockIdx.x;
    const int xcd  = orig & 7;
    const int idx  = orig >> 3;
    const int bid  = (xcd < 4 ? xcd * 145 : 580 + (xcd - 4) * 144) + idx;

    const int b   = bid / NWIN;
    const int win = bid - b * NWIN;
    const int wi  = win / NWROW;
    const int wj  = win - wi * NWROW;
    const int hbase = wi * 8 - 4;
    const int wbase = wj * 8 - 4;

    // ---------------- phase 0: stage x tile (bf16 [pos][ch]) ----------------
    #pragma unroll
    for (int i = 0; i < 8; ++i) {
        int id = (i << 9) + t;
        int ch = id >> 4;
        int qd = id & 15;           // hh = qd>>1, wquad = qd&1
        int h  = hbase + (qd >> 1);
        int w0 = wbase + (qd & 1) * 4;
        f32x4 v = (f32x4){0.f, 0.f, 0.f, 0.f};
        if ((unsigned)h < 128u && (unsigned)w0 < 125u)
            v = *(const f32x4*)&x[(((size_t)b * 256 + ch) * 128 + h) * 128 + w0];
        ushort bs[4] = {f2bf(v[0]), f2bf(v[1]), f2bf(v[2]), f2bf(v[3])};
        #pragma unroll
        for (int e = 0; e < 4; ++e) {
            int ee = (e + qd) & 3;
            sm[(qd * 4 + ee) * XS_STRIDE + ch] = bs[ee];
        }
    }
    __syncthreads();   // B0

    ushort* priv = &sm[XS_SIZE + wv * WPRIV];

    // ---------------- pass A: q,k projection (4 m-tiles x 4 p-tiles) ----------------
    f32x4 acc[4][4];
    #pragma unroll
    for (int i = 0; i < 4; ++i)
        #pragma unroll
        for (int j = 0; j < 4; ++j)
            acc[i][j] = (f32x4){0.f, 0.f, 0.f, 0.f};

    const ushort* wr[4];
    #pragma unroll
    for (int j = 0; j < 4; ++j) {
        int m0 = (j >> 1) * 256 + head * 32 + (j & 1) * 16;   // sect 0=q,1=k
        wr[j] = wqkvb + (size_t)(m0 + c) * 256;
    }

    #pragma unroll
    for (int ks = 0; ks < 8; ++ks) {
        bf16x8 bfr[4];
        #pragma unroll
        for (int pt = 0; pt < 4; ++pt)
            bfr[pt] = *(const bf16x8*)&sm[(pt * 16 + c) * XS_STRIDE + ks * 32 + 8 * g];
        #pragma unroll
        for (int j = 0; j < 4; ++j) {
            bf16x8 afr = *(const bf16x8*)(wr[j] + ks * 32 + 8 * g);
            #pragma unroll
            for (int pt = 0; pt < 4; ++pt)
                acc[j][pt] = __builtin_amdgcn_mfma_f32_16x16x32_bf16(afr, bfr[pt], acc[j][pt], 0, 0, 0);
        }
    }

    // q epilogue -> Qt[pos][32d] stride 40 (injective: row len 32 <= 40)
    #pragma unroll
    for (int mt = 0; mt < 2; ++mt) {
        f32x4 bq = *(const f32x4*)&bqkv[head * 32 + mt * 16 + 4 * g];
        #pragma unroll
        for (int pt = 0; pt < 4; ++pt) {
            const int pos = pt * 16 + c;
            const float* pb = posb + (size_t)(head * 32 + mt * 16 + 4 * g) * 64 + pos;
            float v0 = (acc[mt][pt][0] + bq[0] + pb[0])   * ATT_SCALE;
            float v1 = (acc[mt][pt][1] + bq[1] + pb[64])  * ATT_SCALE;
            float v2 = (acc[mt][pt][2] + bq[2] + pb[128]) * ATT_SCALE;
            float v3 = (acc[mt][pt][3] + bq[3] + pb[192]) * ATT_SCALE;
            *(unsigned*)&priv[pos * 40 + mt * 16 + 4 * g]     = pack2(v0, v1);
            *(unsigned*)&priv[pos * 40 + mt * 16 + 4 * g + 2] = pack2(v2, v3);
        }
    }
    bf16x8 qf[4];
    #pragma unroll
    for (int qt = 0; qt < 4; ++qt)
        qf[qt] = *(const bf16x8*)&priv[(qt * 16 + c) * 40 + 8 * g];

    // k epilogue -> Kt (same slots; same-wave RAW through in-order DS pipe)
    #pragma unroll
    for (int mt = 0; mt < 2; ++mt) {
        f32x4 bk = *(const f32x4*)&bqkv[256 + head * 32 + mt * 16 + 4 * g];
        #pragma unroll
        for (int pt = 0; pt < 4; ++pt) {
            const int pos = pt * 16 + c;
            *(unsigned*)&priv[pos * 40 + mt * 16 + 4 * g]     = pack2(acc[mt + 2][pt][0] + bk[0], acc[mt + 2][pt][1] + bk[1]);
            *(unsigned*)&priv[pos * 40 + mt * 16 + 4 * g + 2] = pack2(acc[mt + 2][pt][2] + bk[2], acc[mt + 2][pt][3] + bk[3]);
        }
    }
    bf16x8 kf[4];
    #pragma unroll
    for (int kt = 0; kt < 4; ++kt)
        kf[kt] = *(const bf16x8*)&priv[(kt * 16 + c) * 40 + 8 * g];

    // ---------------- pass B: v projection (2 m-tiles x 4 p-tiles) ----------------
    f32x4 av[2][4];
    #pragma unroll
    for (int i = 0; i < 2; ++i)
        #pragma unroll
        for (int j = 0; j < 4; ++j)
            av[i][j] = (f32x4){0.f, 0.f, 0.f, 0.f};
    const ushort* wv0 = wqkvb + (size_t)(512 + head * 32 + c) * 256;
    const ushort* wv1 = wqkvb + (size_t)(512 + head * 32 + 16 + c) * 256;

    #pragma unroll
    for (int ks = 0; ks < 8; ++ks) {
        bf16x8 bfr[4];
        #pragma unroll
        for (int pt = 0; pt < 4; ++pt)
            bfr[pt] = *(const bf16x8*)&sm[(pt * 16 + c) * XS_STRIDE + ks * 32 + 8 * g];
        bf16x8 a0 = *(const bf16x8*)(wv0 + ks * 32 + 8 * g);
        bf16x8 a1 = *(const bf16x8*)(wv1 + ks * 32 + 8 * g);
        #pragma unroll
        for (int pt = 0; pt < 4; ++pt) {
            av[0][pt] = __builtin_amdgcn_mfma_f32_16x16x32_bf16(a0, bfr[pt], av[0][pt], 0, 0, 0);
            av[1][pt] = __builtin_amdgcn_mfma_f32_16x16x32_bf16(a1, bfr[pt], av[1][pt], 0, 0, 0);
        }
    }

    // v epilogue -> VT[32 d][64 pos] STRIDE 72 (injective; overwrites Qt/Kt)
    #pragma unroll
    for (int mt = 0; mt < 2; ++mt) {
        f32x4 bv = *(const f32x4*)&bqkv[512 + head * 32 + mt * 16 + 4 * g];
        #pragma unroll
        for (int pt = 0; pt < 4; ++pt) {
            #pragma unroll
            for (int r = 0; r < 4; ++r)
                priv[(mt * 16 + 4 * g + r) * 72 + pt * 16 + c] = f2bf(av[mt][pt][r] + bv[r]);
        }
    }

    // ---------------- attention (fully wave-private, no barriers) ----------------
    f32x4 s[4][4];   // [kt][qt]: D row = key kt*16+4g+r, col = query qt*16+c
    #pragma unroll
    for (int kt = 0; kt < 4; ++kt)
        #pragma unroll
        for (int qt = 0; qt < 4; ++qt)
            s[kt][qt] = __builtin_amdgcn_mfma_f32_16x16x32_bf16(kf[kt], qf[qt],
                                                                (f32x4){0.f,0.f,0.f,0.f}, 0, 0, 0);

    float rinv[4];
    #pragma unroll
    for (int qt = 0; qt < 4; ++qt) {
        float mx = s[0][qt][0];
        #pragma unroll
        for (int kt = 0; kt < 4; ++kt)
            #pragma unroll
            for (int r = 0; r < 4; ++r)
                mx = fmaxf(mx, s[kt][qt][r]);
        mx = fmaxf(mx, __shfl_xor(mx, 16));
        mx = fmaxf(mx, __shfl_xor(mx, 32));
        float sum = 0.f;
        #pragma unroll
        for (int kt = 0; kt < 4; ++kt)
            #pragma unroll
            for (int r = 0; r < 4; ++r) {
                s[kt][qt][r] = __expf(s[kt][qt][r] - mx);
                sum += s[kt][qt][r];
            }
        sum += __shfl_xor(sum, 16);
        sum += __shfl_xor(sum, 32);
        rinv[qt] = 1.0f / sum;
    }

    // vf BEFORE P overwrites VT
    bf16x8 vf[2][2];
    #pragma unroll
    for (int dt = 0; dt < 2; ++dt)
        #pragma unroll
        for (int k2 = 0; k2 < 2; ++k2)
            vf[dt][k2] = *(const bf16x8*)&priv[(dt * 16 + c) * 72 + k2 * 32 + 8 * g];

    // PV in two sequential key-half generations through the same P slots
    f32x4 o[2][4];
    #pragma unroll
    for (int dt = 0; dt < 2; ++dt)
        #pragma unroll
        for (int qt = 0; qt < 4; ++qt)
            o[dt][qt] = (f32x4){0.f,0.f,0.f,0.f};

    #pragma unroll
    for (int k2 = 0; k2 < 2; ++k2) {
        #pragma unroll
        for (int qt = 0; qt < 4; ++qt)
            #pragma unroll
            for (int kl = 0; kl < 2; ++kl) {
                const int kt = k2 * 2 + kl;
                *(unsigned*)&priv[(qt * 16 + c) * 40 + kl * 16 + 4 * g]     = pack2(s[kt][qt][0], s[kt][qt][1]);
                *(unsigned*)&priv[(qt * 16 + c) * 40 + kl * 16 + 4 * g + 2] = pack2(s[kt][qt][2], s[kt][qt][3]);
            }
        #pragma unroll
        for (int qt = 0; qt < 4; ++qt) {
            bf16x8 pf = *(const bf16x8*)&priv[(qt * 16 + c) * 40 + 8 * g];
            #pragma unroll
            for (int dt = 0; dt < 2; ++dt)
                o[dt][qt] = __builtin_amdgcn_mfma_f32_16x16x32_bf16(vf[dt][k2], pf, o[dt][qt], 0, 0, 0);
        }
    }

    __syncthreads();   // B1: every wave done reading xs; o may overlay it

    // o -> os[pos][ch] (xs overlay)
    #pragma unroll
    for (int dt = 0; dt < 2; ++dt)
        #pragma unroll
        for (int qt = 0; qt < 4; ++qt) {
            const int pos = qt * 16 + c;
            const int ch0 = head * 32 + dt * 16 + 4 * g;
            float rv = rinv[qt];
            *(unsigned*)&sm[pos * XS_STRIDE + ch0]     = pack2(o[dt][qt][0]*rv, o[dt][qt][1]*rv);
            *(unsigned*)&sm[pos * XS_STRIDE + ch0 + 2] = pack2(o[dt][qt][2]*rv, o[dt][qt][3]*rv);
        }
    __syncthreads();   // B2: os complete

    // ---------------- out projection: wave owns out-ch wv*32..+31, K=256 ----------------
    f32x4 ya[2][4];
    #pragma unroll
    for (int i = 0; i < 2; ++i)
        #pragma unroll
        for (int j = 0; j < 4; ++j)
            ya[i][j] = (f32x4){0.f,0.f,0.f,0.f};

    const ushort* wo0 = woutb + (size_t)(wv * 32 + c) * 256;
    const ushort* wo1 = woutb + (size_t)(wv * 32 + 16 + c) * 256;

    #pragma unroll
    for (int ks = 0; ks < 8; ++ks) {
        bf16x8 ofr[4];
        #pragma unroll
        for (int pt = 0; pt < 4; ++pt)
            ofr[pt] = *(const bf16x8*)&sm[(pt * 16 + c) * XS_STRIDE + ks * 32 + 8 * g];
        bf16x8 a0 = *(const bf16x8*)(wo0 + ks * 32 + 8 * g);
        bf16x8 a1 = *(const bf16x8*)(wo1 + ks * 32 + 8 * g);
        #pragma unroll
        for (int pt = 0; pt < 4; ++pt) {
            ya[0][pt] = __builtin_amdgcn_mfma_f32_16x16x32_bf16(a0, ofr[pt], ya[0][pt], 0, 0, 0);
            ya[1][pt] = __builtin_amdgcn_mfma_f32_16x16x32_bf16(a1, ofr[pt], ya[1][pt], 0, 0, 0);
        }
    }
    // NO B3: y-transpose scratch is the wave's private slice (priv dead after PV)

    // ---------------- epilogue: per-wave transpose in priv -> float4 y stores ----------------
    float* ysp = (float*)priv;        // [16 rows][66] f32 = 4224B <= 5120B, wave-private
    #pragma unroll
    for (int mt = 0; mt < 2; ++mt) {
        f32x4 bo = *(const f32x4*)&bout[wv * 32 + mt * 16 + 4 * g];
        #pragma unroll
        for (int pt = 0; pt < 4; ++pt) {
            const int pos = pt * 16 + c;
            #pragma unroll
            for (int r = 0; r < 4; ++r)
                ysp[(4 * g + r) * 66 + pos] = ya[mt][pt][r] + bo[r];
        }
        #pragma unroll
        for (int k = 0; k < 2; ++k) {
            const int cl = k * 8 + (lane >> 3);   // 0..15 local out-channel
            const int hh = lane & 7;
            float2 p0 = *(float2*)&ysp[cl * 66 + hh * 8];
            float2 p1 = *(float2*)&ysp[cl * 66 + hh * 8 + 2];
            float2 p2 = *(float2*)&ysp[cl * 66 + hh * 8 + 4];
            float2 p3 = *(float2*)&ysp[cl * 66 + hh * 8 + 6];
            const int co  = wv * 32 + mt * 16 + cl;
            const int him = wi * 8 + hh - 4;
            if ((unsigned)him < 128u) {
                float* yrow = y + (((size_t)b * 256 + co) * 128 + him) * 128;
                if (wj > 0)  { f32x4 v0 = {p0.x, p0.y, p1.x, p1.y}; *(f32x4*)&yrow[wbase]     = v0; }
                if (wj < 16) { f32x4 v1 = {p2.x, p2.y, p3.x, p3.y}; *(f32x4*)&yrow[wbase + 4] = v1; }
            }
        }
    }
}

extern "C" void kernel_launch(void* const* d_in, const int* in_sizes, int n_in,
                              void* d_out, int out_size, void* d_ws, size_t ws_size,
                              hipStream_t stream)
{
    const float* x    = (const float*)d_in[0];
    const float* wqkv = (const float*)d_in[1];
    const float* bqkv = (const float*)d_in[2];
    const float* posb = (const float*)d_in[3];
    const float* wout = (const float*)d_in[4];
    const float* bout = (const float*)d_in[5];
    float* y = (float*)d_out;

    ushort* wqkvb = (ushort*)d_ws;            // 196608 bf16
    ushort* woutb = wqkvb + 196608;           // 65536 bf16

    lsa_wconv<<<dim3(256), dim3(256), 0, stream>>>(wqkv, wout, wqkvb);
    lsa_fused<<<dim3(4 * NWIN), dim3(512), 0, stream>>>(x, bqkv, posb, bout, wqkvb, woutb, y);
}